// Round 1
// baseline (167.030 us; speedup 1.0000x reference)
//
#include <hip/hip_runtime.h>
#include <math.h>

#define BATCH 64
#define NNODE 1024
#define FDIM 64
#define DEG 8
#define ALPHA 0.2f

// ---------------- Kernel 1: h = atoms @ W ; s1 = h.a1 ; s2 = h.a2 ----------
// One wave (64 lanes) per row (b,i). 4 waves per block. W staged in LDS.
__global__ __launch_bounds__(256) void gat_k1(
    const float* __restrict__ atoms,   // (B*N, 64)
    const float* __restrict__ W,       // (64, 64)
    const float* __restrict__ a,       // (128,)
    float* __restrict__ h,             // (B*N, 64)
    float* __restrict__ s1,            // (B*N)
    float* __restrict__ s2)            // (B*N)
{
    __shared__ float Wl[FDIM * FDIM];  // 16 KB
    const int tid = threadIdx.x;

    // cooperative load of W (4096 floats) via float4: 1024 float4, 256 threads
    {
        const float4* W4  = (const float4*)W;
        float4*       Wl4 = (float4*)Wl;
        #pragma unroll
        for (int i = 0; i < 4; ++i)
            Wl4[tid + 256 * i] = W4[tid + 256 * i];
    }
    __syncthreads();

    const int wave = tid >> 6;
    const int lane = tid & 63;
    const int row  = blockIdx.x * 4 + wave;      // 0 .. B*N-1

    // lane t holds atoms[row][t]; broadcast each k via shuffle
    const float av = atoms[row * FDIM + lane];
    float acc = 0.f;
    #pragma unroll
    for (int k = 0; k < FDIM; ++k) {
        const float ak = __shfl(av, k, 64);
        acc = fmaf(ak, Wl[k * FDIM + lane], acc);
    }
    h[row * FDIM + lane] = acc;

    // wave-reduce s1 = sum_t acc*a1[t], s2 = sum_t acc*a2[t]
    float p1 = acc * a[lane];
    float p2 = acc * a[FDIM + lane];
    #pragma unroll
    for (int off = 32; off > 0; off >>= 1) {
        p1 += __shfl_xor(p1, off, 64);
        p2 += __shfl_xor(p2, off, 64);
    }
    if (lane == 0) { s1[row] = p1; s2[row] = p2; }
}

// ---------------- Kernel 2: masked softmax over <=8 unique neighbors -------
// One wave per row; lane t owns output feature t.
__global__ __launch_bounds__(256) void gat_k2(
    const float* __restrict__ h,       // (B*N, 64)
    const float* __restrict__ s1,      // (B*N)
    const float* __restrict__ s2,      // (B*N)
    const int*   __restrict__ edges,   // (B*N, 8) int32
    float* __restrict__ out)           // (B*N, 64)
{
    const int tid  = threadIdx.x;
    const int wave = tid >> 6;
    const int lane = tid & 63;
    const int row  = blockIdx.x * 4 + wave;   // 0 .. B*N-1
    const int b    = row >> 10;               // N = 1024

    // wave-uniform: 8 neighbor indices
    int ej[DEG];
    const int* ep = edges + (long long)row * DEG;
    #pragma unroll
    for (int k = 0; k < DEG; ++k) ej[k] = ep[k];

    // dedupe: keep[k] iff no earlier duplicate (adj is boolean in the ref)
    bool keep[DEG];
    #pragma unroll
    for (int k = 0; k < DEG; ++k) {
        bool kp = true;
        #pragma unroll
        for (int m = 0; m < DEG; ++m)
            if (m < k && ej[m] == ej[k]) kp = false;
        keep[k] = kp;
    }

    const float si = s1[row];
    float e[DEG];
    float mx = -INFINITY;
    #pragma unroll
    for (int k = 0; k < DEG; ++k) {
        float v = si + s2[b * NNODE + ej[k]];
        v = (v > 0.f) ? v : ALPHA * v;          // LeakyReLU
        e[k] = v;
        mx = fmaxf(mx, v);                      // dups have equal v; max unaffected
    }

    float wgt[DEG];
    float wsum = 0.f;
    #pragma unroll
    for (int k = 0; k < DEG; ++k) {
        const float w = keep[k] ? expf(e[k] - mx) : 0.f;
        wgt[k] = w;
        wsum += w;
    }
    const float inv = 1.f / wsum;

    float acc = 0.f;
    #pragma unroll
    for (int k = 0; k < DEG; ++k) {
        const float c = wgt[k] * inv;           // 0 for dropped duplicates
        acc = fmaf(c, h[((long long)b * NNODE + ej[k]) * FDIM + lane], acc);
    }

    // ELU (alpha = 1)
    out[(long long)row * FDIM + lane] = (acc > 0.f) ? acc : (expf(acc) - 1.f);
}

extern "C" void kernel_launch(void* const* d_in, const int* in_sizes, int n_in,
                              void* d_out, int out_size, void* d_ws, size_t ws_size,
                              hipStream_t stream) {
    const float* atoms = (const float*)d_in[0];   // (64,1024,64) f32
    const int*   edges = (const int*)d_in[1];     // (64,1024,8) int32
    const float* W     = (const float*)d_in[2];   // (64,64) f32
    const float* a     = (const float*)d_in[3];   // (128,1) f32
    float* out = (float*)d_out;                   // (64,1024,64) f32

    const int rows = BATCH * NNODE;               // 65536

    // workspace layout
    float* h  = (float*)d_ws;                     // rows*64 floats = 16.78 MB
    float* s1 = h + (size_t)rows * FDIM;          // rows floats
    float* s2 = s1 + rows;                        // rows floats

    const int blocks = rows / 4;                  // 4 waves (rows) per block
    gat_k1<<<blocks, 256, 0, stream>>>(atoms, W, a, h, s1, s2);
    gat_k2<<<blocks, 256, 0, stream>>>(h, s1, s2, edges, out);
}

// Round 2
// 114.342 us; speedup vs baseline: 1.4608x; 1.4608x over previous
//
#include <hip/hip_runtime.h>
#include <math.h>

#define BATCH 64
#define NNODE 1024
#define FDIM 64
#define DEG 8
#define ALPHA 0.2f
#define ROWS_K1 8   // rows per wave in k1
#define ROWS_K2 4   // rows per wave in k2

// ---------------- Kernel 1: h = atoms @ W ; s1 = h.a1 ; s2 = h.a2 ----------
// 4 waves/block, ROWS_K1 rows per wave. W column held in VGPRs; atoms row
// read via wave-uniform (scalar) loads -> broadcast operand of v_fmac.
__global__ __launch_bounds__(256) void gat_k1(
    const float* __restrict__ atoms,   // (B*N, 64)
    const float* __restrict__ W,       // (64, 64)
    const float* __restrict__ a,       // (128,)
    float* __restrict__ h,             // (B*N, 64)
    float* __restrict__ s1,            // (B*N)
    float* __restrict__ s2)            // (B*N)
{
    const int lane = threadIdx.x & 63;
    // force wave id uniform so row-derived addresses scalarize
    const int wave = __builtin_amdgcn_readfirstlane(threadIdx.x >> 6);
    const int base = (blockIdx.x * 4 + wave) * ROWS_K1;

    // W column for this lane: Wc[k] = W[k][lane]  (64 VGPRs)
    float Wc[FDIM];
    #pragma unroll
    for (int k = 0; k < FDIM; ++k) Wc[k] = W[k * FDIM + lane];

    const float a1l = a[lane];
    const float a2l = a[FDIM + lane];

    for (int r = 0; r < ROWS_K1; ++r) {
        const int row = base + r;                       // wave-uniform
        const float* __restrict__ ar = atoms + (size_t)row * FDIM;
        float acc = 0.f;
        #pragma unroll
        for (int k = 0; k < FDIM; ++k)
            acc = fmaf(ar[k], Wc[k], acc);              // ar[k] scalar-broadcast
        h[(size_t)row * FDIM + lane] = acc;

        float p1 = acc * a1l;
        float p2 = acc * a2l;
        #pragma unroll
        for (int off = 32; off > 0; off >>= 1) {
            p1 += __shfl_xor(p1, off, 64);
            p2 += __shfl_xor(p2, off, 64);
        }
        if (lane == 0) { s1[row] = p1; s2[row] = p2; }
    }
}

// ---------------- Kernel 2: masked softmax over <=8 unique neighbors -------
// 4 waves/block, ROWS_K2 rows per wave; loads hoisted for MLP.
__global__ __launch_bounds__(256) void gat_k2(
    const float* __restrict__ h,       // (B*N, 64)
    const float* __restrict__ s1,      // (B*N)
    const float* __restrict__ s2,      // (B*N)
    const int*   __restrict__ edges,   // (B*N, 8) int32
    float* __restrict__ out)           // (B*N, 64)
{
    const int lane = threadIdx.x & 63;
    const int wave = __builtin_amdgcn_readfirstlane(threadIdx.x >> 6);
    const int base = (blockIdx.x * 4 + wave) * ROWS_K2;
    const int b    = base >> 10;                        // rows of a wave share batch

    // edge indices for all rows (uniform -> SGPRs)
    int ej[ROWS_K2][DEG];
    #pragma unroll
    for (int r = 0; r < ROWS_K2; ++r) {
        const int* __restrict__ ep = edges + (size_t)(base + r) * DEG;
        #pragma unroll
        for (int k = 0; k < DEG; ++k) ej[r][k] = ep[k];
    }

    // scores (uniform scalar loads)
    float si[ROWS_K2], sj[ROWS_K2][DEG];
    #pragma unroll
    for (int r = 0; r < ROWS_K2; ++r) {
        si[r] = s1[base + r];
        #pragma unroll
        for (int k = 0; k < DEG; ++k)
            sj[r][k] = s2[b * NNODE + ej[r][k]];
    }

    // softmax weights per row (computed redundantly in all lanes; cheap)
    float wgt[ROWS_K2][DEG];
    #pragma unroll
    for (int r = 0; r < ROWS_K2; ++r) {
        float e[DEG], mx = -INFINITY;
        #pragma unroll
        for (int k = 0; k < DEG; ++k) {
            float v = si[r] + sj[r][k];
            v = (v > 0.f) ? v : ALPHA * v;              // LeakyReLU
            e[k] = v;
            mx = fmaxf(mx, v);
        }
        float wsum = 0.f;
        #pragma unroll
        for (int k = 0; k < DEG; ++k) {
            // dedupe: adj is boolean in the reference — duplicates count once
            bool kp = true;
            #pragma unroll
            for (int m = 0; m < DEG; ++m)
                if (m < k && ej[r][m] == ej[r][k]) kp = false;
            const float w = kp ? __expf(e[k] - mx) : 0.f;
            wgt[r][k] = w;
            wsum += w;
        }
        const float inv = 1.f / wsum;
        #pragma unroll
        for (int k = 0; k < DEG; ++k) wgt[r][k] *= inv;
    }

    // gather + accumulate + ELU + store
    #pragma unroll
    for (int r = 0; r < ROWS_K2; ++r) {
        float acc = 0.f;
        #pragma unroll
        for (int k = 0; k < DEG; ++k) {
            const float hv = h[((size_t)b * NNODE + ej[r][k]) * FDIM + lane];
            acc = fmaf(wgt[r][k], hv, acc);
        }
        out[(size_t)(base + r) * FDIM + lane] = (acc > 0.f) ? acc : (__expf(acc) - 1.f);
    }
}

extern "C" void kernel_launch(void* const* d_in, const int* in_sizes, int n_in,
                              void* d_out, int out_size, void* d_ws, size_t ws_size,
                              hipStream_t stream) {
    const float* atoms = (const float*)d_in[0];   // (64,1024,64) f32
    const int*   edges = (const int*)d_in[1];     // (64,1024,8) int32
    const float* W     = (const float*)d_in[2];   // (64,64) f32
    const float* a     = (const float*)d_in[3];   // (128,1) f32
    float* out = (float*)d_out;                   // (64,1024,64) f32

    const int rows = BATCH * NNODE;               // 65536

    float* h  = (float*)d_ws;                     // rows*64 floats
    float* s1 = h + (size_t)rows * FDIM;
    float* s2 = s1 + rows;

    const int blocks_k1 = rows / (4 * ROWS_K1);   // 2048
    const int blocks_k2 = rows / (4 * ROWS_K2);   // 4096
    gat_k1<<<blocks_k1, 256, 0, stream>>>(atoms, W, a, h, s1, s2);
    gat_k2<<<blocks_k2, 256, 0, stream>>>(h, s1, s2, edges, out);
}

// Round 3
// 102.687 us; speedup vs baseline: 1.6266x; 1.1135x over previous
//
#include <hip/hip_runtime.h>
#include <math.h>

#define BATCH 64
#define NNODE 1024
#define FDIM 64
#define DEG 8
#define ALPHA 0.2f

typedef __attribute__((ext_vector_type(8))) short bf16x8;  // 8 bf16 in 4 VGPRs
typedef __attribute__((ext_vector_type(4))) float f32x4;

__device__ __forceinline__ short f2bf(float f) {
    union { float f; unsigned u; } v; v.f = f;
    unsigned r = v.u + 0x7fffu + ((v.u >> 16) & 1u);   // RNE
    return (short)(r >> 16);
}

// ---------------- k0: wa1 = W @ a1, wa2 = W @ a2  (64x64 matvec, 1 block) ---
__global__ void gat_k0(const float* __restrict__ W, const float* __restrict__ a,
                       float* __restrict__ wa) {
    const int k = threadIdx.x;            // 0..63
    float p1 = 0.f, p2 = 0.f;
    #pragma unroll
    for (int j = 0; j < FDIM; ++j) {
        const float w = W[k * FDIM + j];
        p1 = fmaf(w, a[j], p1);
        p2 = fmaf(w, a[FDIM + j], p2);
    }
    wa[k] = p1; wa[FDIM + k] = p2;
}

// ---------------- k1: h = bf16MFMA(atoms, W); s1,s2 via extra B-tile -------
// One wave computes 16 rows x 64 cols. 4 waves/block -> 64 rows/block.
__global__ __launch_bounds__(256) void gat_k1(
    const float* __restrict__ atoms,   // (B*N, 64)
    const float* __restrict__ W,       // (64, 64)
    const float* __restrict__ wa,      // (128,)  [wa1 | wa2]
    float* __restrict__ h,             // (B*N, 64)
    float* __restrict__ s1,            // (B*N)
    float* __restrict__ s2)            // (B*N)
{
    const int lane = threadIdx.x & 63;
    const int wv   = threadIdx.x >> 6;
    const int l16  = lane & 15;        // A: m, B: n, C: col
    const int qd   = lane >> 4;        // k-quad
    const int rowbase = (blockIdx.x * 4 + wv) * 16;

    // B-frags of W: Bw[ks][t][j] = W[ks*32 + qd*8 + j][t*16 + l16]
    bf16x8 Bw[2][4];
    #pragma unroll
    for (int ks = 0; ks < 2; ++ks)
        #pragma unroll
        for (int t = 0; t < 4; ++t)
            #pragma unroll
            for (int j = 0; j < 8; ++j)
                Bw[ks][t][j] = f2bf(W[(ks * 32 + qd * 8 + j) * FDIM + t * 16 + l16]);

    // score B-frag: col0 = wa1[k], col1 = wa2[k], cols 2..15 = 0
    bf16x8 Bs[2];
    #pragma unroll
    for (int ks = 0; ks < 2; ++ks)
        #pragma unroll
        for (int j = 0; j < 8; ++j) {
            const int k = ks * 32 + qd * 8 + j;
            const float v = (l16 == 0) ? wa[k] : ((l16 == 1) ? wa[FDIM + k] : 0.f);
            Bs[ks][j] = f2bf(v);
        }

    // A-frags: A[m = l16][k = ks*32 + qd*8 + j], m-row = rowbase + l16
    const float* __restrict__ ar = atoms + (size_t)(rowbase + l16) * FDIM;
    bf16x8 A[2];
    #pragma unroll
    for (int ks = 0; ks < 2; ++ks) {
        const float4 p0 = *(const float4*)(ar + ks * 32 + qd * 8);
        const float4 p1 = *(const float4*)(ar + ks * 32 + qd * 8 + 4);
        A[ks][0] = f2bf(p0.x); A[ks][1] = f2bf(p0.y);
        A[ks][2] = f2bf(p0.z); A[ks][3] = f2bf(p0.w);
        A[ks][4] = f2bf(p1.x); A[ks][5] = f2bf(p1.y);
        A[ks][6] = f2bf(p1.z); A[ks][7] = f2bf(p1.w);
    }

    f32x4 C[4] = {{0,0,0,0},{0,0,0,0},{0,0,0,0},{0,0,0,0}};
    f32x4 Cs = {0,0,0,0};
    #pragma unroll
    for (int ks = 0; ks < 2; ++ks) {
        #pragma unroll
        for (int t = 0; t < 4; ++t)
            C[t] = __builtin_amdgcn_mfma_f32_16x16x32_bf16(A[ks], Bw[ks][t], C[t], 0, 0, 0);
        Cs = __builtin_amdgcn_mfma_f32_16x16x32_bf16(A[ks], Bs[ks], Cs, 0, 0, 0);
    }

    // C/D layout: col = l16, row = qd*4 + reg
    #pragma unroll
    for (int t = 0; t < 4; ++t)
        #pragma unroll
        for (int r = 0; r < 4; ++r)
            h[(size_t)(rowbase + qd * 4 + r) * FDIM + t * 16 + l16] = C[t][r];

    if (l16 < 2) {
        float* sp = (l16 == 0) ? s1 : s2;
        #pragma unroll
        for (int r = 0; r < 4; ++r)
            sp[rowbase + qd * 4 + r] = Cs[r];
    }
}

// ---------------- k2: LDS-staged masked softmax + gather-accumulate --------
// Block = 64 rows of one batch. s2[b] (4KB) + edges (2KB) + s1 (256B) in LDS.
__global__ __launch_bounds__(256) void gat_k2(
    const float* __restrict__ h,       // (B*N, 64)
    const float* __restrict__ s1g,     // (B*N)
    const float* __restrict__ s2g,     // (B*N)
    const int*   __restrict__ edges,   // (B*N, 8) int32
    float* __restrict__ out)           // (B*N, 64)
{
    __shared__ float s2l[NNODE];
    __shared__ int   el[64 * DEG];
    __shared__ float s1l[64];

    // XCD swizzle: all 16 chunks of batch b land on XCD b&7 -> h-slice L2-hot
    const int bid   = blockIdx.x;
    const int slot  = bid >> 3;
    const int b     = (bid & 7) + 8 * (slot & 7);   // 0..63
    const int chunk = slot >> 3;                    // 0..15
    const int rowbase = b * NNODE + chunk * 64;

    const int tid = threadIdx.x;
    ((float4*)s2l)[tid] = ((const float4*)(s2g + b * NNODE))[tid];          // 4KB
    ((int2*)el)[tid]    = ((const int2*)(edges + (size_t)rowbase * DEG))[tid]; // 2KB
    if (tid < 64) s1l[tid] = s1g[rowbase + tid];
    __syncthreads();

    const int lane = tid & 63;
    const int wv   = tid >> 6;
    const float* __restrict__ hb = h + (size_t)b * NNODE * FDIM;

    #pragma unroll 2
    for (int i = 0; i < 16; ++i) {
        const int rl = wv * 16 + i;                 // row within block
        int ej[DEG];
        #pragma unroll
        for (int k = 0; k < DEG; ++k) ej[k] = el[rl * DEG + k];

        const float si = s1l[rl];
        float e[DEG], mx = -INFINITY;
        #pragma unroll
        for (int k = 0; k < DEG; ++k) {
            float v = si + s2l[ej[k]];
            v = (v > 0.f) ? v : ALPHA * v;          // LeakyReLU
            e[k] = v; mx = fmaxf(mx, v);
        }
        float wgt[DEG], wsum = 0.f;
        #pragma unroll
        for (int k = 0; k < DEG; ++k) {
            bool kp = true;                          // dedupe: adj is boolean
            #pragma unroll
            for (int m = 0; m < DEG; ++m)
                if (m < k && ej[m] == ej[k]) kp = false;
            const float w = kp ? __expf(e[k] - mx) : 0.f;
            wgt[k] = w; wsum += w;
        }
        const float inv = 1.f / wsum;

        float acc = 0.f;
        #pragma unroll
        for (int k = 0; k < DEG; ++k)
            acc = fmaf(wgt[k] * inv, hb[(size_t)ej[k] * FDIM + lane], acc);

        out[(size_t)(rowbase + rl) * FDIM + lane] = (acc > 0.f) ? acc : (__expf(acc) - 1.f);
    }
}

extern "C" void kernel_launch(void* const* d_in, const int* in_sizes, int n_in,
                              void* d_out, int out_size, void* d_ws, size_t ws_size,
                              hipStream_t stream) {
    const float* atoms = (const float*)d_in[0];   // (64,1024,64) f32
    const int*   edges = (const int*)d_in[1];     // (64,1024,8) int32
    const float* W     = (const float*)d_in[2];   // (64,64) f32
    const float* a     = (const float*)d_in[3];   // (128,1) f32
    float* out = (float*)d_out;                   // (64,1024,64) f32

    const int rows = BATCH * NNODE;               // 65536

    float* h  = (float*)d_ws;                     // rows*64 floats
    float* s1 = h + (size_t)rows * FDIM;          // rows
    float* s2 = s1 + rows;                        // rows
    float* wa = s2 + rows;                        // 128

    gat_k0<<<1, 64, 0, stream>>>(W, a, wa);
    gat_k1<<<rows / 64, 256, 0, stream>>>(atoms, W, wa, h, s1, s2);
    gat_k2<<<rows / 64, 256, 0, stream>>>(h, s1, s2, edges, out);
}